// Round 5
// baseline (717.532 us; speedup 1.0000x reference)
//
#include <hip/hip_runtime.h>

#define NN 100000
#define NE 1600000
#define SCAN_NB 98   // ceil(NN / 1024)

typedef __attribute__((ext_vector_type(8))) short bf16x8;
typedef __attribute__((ext_vector_type(4))) float floatx4;

static __device__ __forceinline__ float bitsf(unsigned u) {
    union { unsigned u; float f; } t; t.u = u; return t.f;
}
static __device__ __forceinline__ unsigned fbits(float f) {
    union { float f; unsigned u; } t; t.f = f; return t.u;
}

static __device__ __forceinline__ unsigned short f2bf(float f) {
    union { float f; unsigned u; } t; t.f = f;
    unsigned r = t.u + 0x7fffu + ((t.u >> 16) & 1u);  // RNE
    return (unsigned short)(r >> 16);
}

// load 4 consecutive bf16 (8B) and widen to f32
static __device__ __forceinline__ void ld_bf4(const unsigned short* p, float* f) {
    uint2 u = *reinterpret_cast<const uint2*>(p);
    f[0] = bitsf(u.x << 16);
    f[1] = bitsf(u.x & 0xffff0000u);
    f[2] = bitsf(u.y << 16);
    f[3] = bitsf(u.y & 0xffff0000u);
}

static __device__ __forceinline__ float ldf(const void* p, int i, int fb) {
    return fb ? bitsf(((unsigned)((const unsigned short*)p)[i]) << 16)
              : ((const float*)p)[i];
}

static __device__ __forceinline__ int ld_row(const int* ei, int e, int i64) {
    return i64 ? ei[2 * e] : ei[e];
}
static __device__ __forceinline__ int ld_col(const int* ei, int e, int i64) {
    return i64 ? ei[2 * NE + 2 * e] : ei[NE + e];
}

// ---- probe input dtypes (deterministic) -----------------------------------
__global__ void k_probe(const unsigned short* __restrict__ xs, const int* __restrict__ ei,
                        int* __restrict__ flags) {
    __shared__ int s_bad[256], s_odd[256];
    int t = threadIdx.x;
    int bad = 0;
    for (int i = 0; i < 16; i++) {
        unsigned short v = xs[t * 16 + i];
        if (((v >> 7) & 0xFF) >= 0xC0) bad++;
    }
    s_bad[t] = bad;
    s_odd[t] = (ei[2 * t + 1] != 0) ? 1 : 0;
    __syncthreads();
    if (t == 0) {
        int B = 0, O = 0;
        for (int i = 0; i < 256; i++) { B += s_bad[i]; O += s_odd[i]; }
        flags[0] = (B < 16) ? 1 : 0;  // 1 = floats stored as bf16
        flags[1] = (O == 0) ? 1 : 0;  // 1 = edge_index stored as int64
    }
}

// ---- deg[c] += ew[e]; cnt[c] += 1 -----------------------------------------
__global__ void k_deg(const int* __restrict__ ei, const void* __restrict__ ew,
                      float* __restrict__ deg, int* __restrict__ cnt,
                      const int* __restrict__ flags) {
    int e = blockIdx.x * 256 + threadIdx.x;
    if (e >= NE) return;
    int fb = flags[0], i64 = flags[1];
    int c = ld_col(ei, e, i64);
    atomicAdd(&deg[c], ldf(ew, e, fb));
    atomicAdd(&cnt[c], 1);
}

__global__ void k_dinv(const float* __restrict__ deg, float* __restrict__ dinv) {
    int n = blockIdx.x * 256 + threadIdx.x;
    if (n < NN) {
        float d = deg[n];
        dinv[n] = (d > 0.f) ? rsqrtf(d) : 0.f;
    }
}

// ---- hierarchical scan: cnt -> ptr (exclusive), cursor --------------------
__global__ void k_scan1(const int* __restrict__ cnt, int* __restrict__ blocksum) {
    __shared__ int s[256];
    int b = blockIdx.x, t = threadIdx.x;
    int base = b * 1024 + t * 4;
    int v = 0;
    if (base + 3 < NN) {
        int4 c = *(const int4*)(cnt + base);
        v = c.x + c.y + c.z + c.w;
    } else {
        for (int i = 0; i < 4; i++) if (base + i < NN) v += cnt[base + i];
    }
    s[t] = v;
    __syncthreads();
    for (int off = 128; off > 0; off >>= 1) {
        if (t < off) s[t] += s[t + off];
        __syncthreads();
    }
    if (t == 0) blocksum[b] = s[0];
}

__global__ void k_scan2(const int* __restrict__ blocksum, int* __restrict__ blockoff) {
    __shared__ int s[128];
    int t = threadIdx.x;
    int v = (t < SCAN_NB) ? blocksum[t] : 0;
    s[t] = v;
    __syncthreads();
    for (int off = 1; off < 128; off <<= 1) {
        int u = (t >= off) ? s[t - off] : 0;
        __syncthreads();
        s[t] += u;
        __syncthreads();
    }
    if (t < SCAN_NB) blockoff[t] = s[t] - v;   // exclusive
    if (t == SCAN_NB - 1) blockoff[SCAN_NB] = s[t];  // total
}

__global__ void k_scan3(const int* __restrict__ cnt, const int* __restrict__ blockoff,
                        int* __restrict__ ptr, int* __restrict__ cursor) {
    __shared__ int s[256];
    int b = blockIdx.x, t = threadIdx.x;
    int base = b * 1024 + t * 4;
    int c[4] = {0, 0, 0, 0};
    if (base + 3 < NN) {
        int4 cc = *(const int4*)(cnt + base);
        c[0] = cc.x; c[1] = cc.y; c[2] = cc.z; c[3] = cc.w;
    } else {
        for (int i = 0; i < 4; i++) if (base + i < NN) c[i] = cnt[base + i];
    }
    int tsum = c[0] + c[1] + c[2] + c[3];
    s[t] = tsum;
    __syncthreads();
    for (int off = 1; off < 256; off <<= 1) {
        int u = (t >= off) ? s[t - off] : 0;
        __syncthreads();
        s[t] += u;
        __syncthreads();
    }
    int run = blockoff[b] + s[t] - tsum;
    int p[4];
#pragma unroll
    for (int i = 0; i < 4; i++) { p[i] = run; run += c[i]; }
    if (base + 3 < NN) {
        int4 pv; pv.x = p[0]; pv.y = p[1]; pv.z = p[2]; pv.w = p[3];
        *(int4*)(ptr + base) = pv;
        *(int4*)(cursor + base) = pv;
    } else {
        for (int i = 0; i < 4; i++) if (base + i < NN) { ptr[base + i] = p[i]; cursor[base + i] = p[i]; }
    }
    if (b == 0 && t == 0) ptr[NN] = blockoff[SCAN_NB];
}

// ---- fill CSR: edgedata[pos] = (row, norm_bits) ----------------------------
__global__ void k_fill(const int* __restrict__ ei, const void* __restrict__ ew,
                       const float* __restrict__ dinv, int* __restrict__ cursor,
                       int2* __restrict__ edgedata, const int* __restrict__ flags) {
    int e = blockIdx.x * 256 + threadIdx.x;
    if (e >= NE) return;
    int fb = flags[0], i64 = flags[1];
    int r = ld_row(ei, e, i64), c = ld_col(ei, e, i64);
    float nw = dinv[r] * ldf(ew, e, fb) * dinv[c];
    int pos = atomicAdd(&cursor[c], 1);
    int2 ed; ed.x = r; ed.y = (int)fbits(nw);
    edgedata[pos] = ed;
}

// ---- h0 = relu(x @ W0^T + b); cur = h0 -------------------------------------
// fb==1 fast path: MFMA. block = 256 = 4 waves; wave handles 16 nodes x 64 feats.
// A-frag: x[node=lane&15][k=quad*8+j] -> contiguous 16B global load.
// B-frag: W0[feat][k=quad*8+j]        -> contiguous 16B global load.
// C/D: row(node)=quad*4+reg, col(feat)=lane&15 -> LDS transpose for coalesced stores.
__global__ void k_h0(const void* __restrict__ x, const void* __restrict__ w0,
                     const void* __restrict__ b0, unsigned short* __restrict__ h0b,
                     void* __restrict__ cur, const int* __restrict__ flags) {
    int fb = flags[0];
    if (fb) {
        __shared__ float s_o[4][16][68];   // [wave][node][feat], +4 pad
        int tid = threadIdx.x;
        int w = tid >> 6, l = tid & 63;
        int quad = l >> 4, m = l & 15;
        int nodebase = blockIdx.x * 64 + w * 16;

        int arow = nodebase + m;
        if (arow > NN - 1) arow = NN - 1;
        const unsigned short* xp = (const unsigned short*)x + (size_t)arow * 64 + quad * 8;
        bf16x8 a_lo = *(const bf16x8*)xp;
        bf16x8 a_hi = *(const bf16x8*)(xp + 32);

        floatx4 acc[4];
#pragma unroll
        for (int t = 0; t < 4; t++) acc[t] = (floatx4){0.f, 0.f, 0.f, 0.f};

        const unsigned short* wp = (const unsigned short*)w0;
#pragma unroll
        for (int t = 0; t < 4; t++) {
            const unsigned short* wrow = wp + (size_t)(t * 16 + m) * 64 + quad * 8;
            bf16x8 b_lo = *(const bf16x8*)wrow;
            bf16x8 b_hi = *(const bf16x8*)(wrow + 32);
            acc[t] = __builtin_amdgcn_mfma_f32_16x16x32_bf16(a_lo, b_lo, acc[t], 0, 0, 0);
            acc[t] = __builtin_amdgcn_mfma_f32_16x16x32_bf16(a_hi, b_hi, acc[t], 0, 0, 0);
        }

        const unsigned short* bp = (const unsigned short*)b0;
#pragma unroll
        for (int t = 0; t < 4; t++) {
            float bias = bitsf(((unsigned)bp[t * 16 + m]) << 16);
#pragma unroll
            for (int r = 0; r < 4; r++) {
                float v = acc[t][r] + bias;
                s_o[w][quad * 4 + r][t * 16 + m] = (v > 0.f) ? v : 0.f;
            }
        }
        __syncthreads();

        int node = l >> 2, chunk = l & 3;   // 16 nodes x 4 chunks of 16 feats
        int gnode = nodebase + node;
        if (gnode < NN) {
            union { unsigned short us[16]; uint4 u4[2]; } ob;
#pragma unroll
            for (int i = 0; i < 16; i += 4) {
                float4 v = *(const float4*)&s_o[w][node][chunk * 16 + i];
                ob.us[i + 0] = f2bf(v.x);
                ob.us[i + 1] = f2bf(v.y);
                ob.us[i + 2] = f2bf(v.z);
                ob.us[i + 3] = f2bf(v.w);
            }
            uint4* hp = (uint4*)(h0b + (size_t)gnode * 64 + chunk * 16);
            hp[0] = ob.u4[0]; hp[1] = ob.u4[1];
            uint4* cp = (uint4*)((unsigned short*)cur + (size_t)gnode * 64 + chunk * 16);
            cp[0] = ob.u4[0]; cp[1] = ob.u4[1];
        }
    } else {
        // f32-input fallback (never taken for this dataset; correctness insurance)
        for (int s = 0; s < 4; s++) {
            int t = blockIdx.x * 1024 + s * 256 + threadIdx.x;
            int n = t >> 4, q = t & 15;
            if (n >= NN) continue;
            float acc[4] = {0.f, 0.f, 0.f, 0.f};
            const float* xp = (const float*)x + (size_t)n * 64;
            const float* wp = (const float*)w0;
            for (int kk = 0; kk < 64; kk += 4) {
                float4 xv = *(const float4*)(xp + kk);
                for (int j = 0; j < 4; j++) {
                    float4 wv = *(const float4*)(wp + (size_t)(q * 4 + j) * 64 + kk);
                    acc[j] += xv.x * wv.x + xv.y * wv.y + xv.z * wv.z + xv.w * wv.w;
                }
            }
            float r[4];
            for (int j = 0; j < 4; j++) {
                float v = acc[j] + ((const float*)b0)[q * 4 + j];
                r[j] = (v > 0.f) ? v : 0.f;
            }
            ushort4 hb;
            hb.x = f2bf(r[0]); hb.y = f2bf(r[1]); hb.z = f2bf(r[2]); hb.w = f2bf(r[3]);
            *(ushort4*)(h0b + (size_t)n * 64 + q * 4) = hb;
            float4 o; o.x = r[0]; o.y = r[1]; o.z = r[2]; o.w = r[3];
            *(float4*)((float*)cur + (size_t)n * 64 + q * 4) = o;
        }
    }
}

// ---- fused conv: gather + (0.1*agg+0.9*h0)@W1 relu + residual --------------
__global__ void k_conv(const int* __restrict__ ptr, const int2* __restrict__ edgedata,
                       const void* __restrict__ cur_in, const unsigned short* __restrict__ h0b,
                       const void* __restrict__ w1, void* __restrict__ cur_out,
                       int layer, const int* __restrict__ flags) {
    __shared__ float s_w[64 * 64];       // 16 KB, W1 as f32
    __shared__ float s_t[16 * 68];       // padded stride 68
    int fb = flags[0];
    int in_bf  = fb ? 1 : (layer == 1);
    int out_bf = fb ? 1 : (layer == 0);

    int tid = threadIdx.x;
    if (fb) {
        const unsigned short* wp = (const unsigned short*)w1 + layer * 4096;
        for (int i = 0; i < 16; i += 4) {
            int idx = tid * 16 + i;
            float wv[4]; ld_bf4(wp + idx, wv);
            s_w[idx] = wv[0]; s_w[idx + 1] = wv[1]; s_w[idx + 2] = wv[2]; s_w[idx + 3] = wv[3];
        }
    } else {
        const float* wp = (const float*)w1 + layer * 4096;
        for (int i = 0; i < 16; i += 4) {
            int idx = tid * 16 + i;
            float4 wv = *(const float4*)(wp + idx);
            s_w[idx] = wv.x; s_w[idx + 1] = wv.y; s_w[idx + 2] = wv.z; s_w[idx + 3] = wv.w;
        }
    }

    int g = tid >> 4, q = tid & 15;
    int n = blockIdx.x * 16 + g;
    float acc[4] = {0.f, 0.f, 0.f, 0.f};
    if (n < NN) {
        int jb = ptr[n], je = ptr[n + 1];
        for (int j = jb; j < je; j++) {
            int2 ed = edgedata[j];
            float w = bitsf((unsigned)ed.y);
            float v[4];
            if (in_bf) {
                ld_bf4((const unsigned short*)cur_in + (size_t)ed.x * 64 + q * 4, v);
            } else {
                float4 f = *(const float4*)((const float*)cur_in + (size_t)ed.x * 64 + q * 4);
                v[0] = f.x; v[1] = f.y; v[2] = f.z; v[3] = f.w;
            }
            acc[0] += v[0] * w; acc[1] += v[1] * w;
            acc[2] += v[2] * w; acc[3] += v[3] * w;
        }
        float hv[4]; ld_bf4(h0b + (size_t)n * 64 + q * 4, hv);
#pragma unroll
        for (int j = 0; j < 4; j++)
            s_t[g * 68 + q * 4 + j] = 0.1f * acc[j] + 0.9f * hv[j];
    }
    __syncthreads();
    if (n >= NN) return;

    float acc2[4] = {0.f, 0.f, 0.f, 0.f};
#pragma unroll 8
    for (int k = 0; k < 64; k++) {
        float tv = s_t[g * 68 + k];
        float4 wv = *(const float4*)(&s_w[k * 64 + q * 4]);
        acc2[0] += tv * wv.x; acc2[1] += tv * wv.y;
        acc2[2] += tv * wv.z; acc2[3] += tv * wv.w;
    }
    float c[4];
    if (in_bf) {
        ld_bf4((const unsigned short*)cur_in + (size_t)n * 64 + q * 4, c);
    } else {
        float4 f = *(const float4*)((const float*)cur_in + (size_t)n * 64 + q * 4);
        c[0] = f.x; c[1] = f.y; c[2] = f.z; c[3] = f.w;
    }
#pragma unroll
    for (int j = 0; j < 4; j++) c[j] += (acc2[j] > 0.f) ? acc2[j] : 0.f;
    if (out_bf) {
        ushort4 o;
        o.x = f2bf(c[0]); o.y = f2bf(c[1]); o.z = f2bf(c[2]); o.w = f2bf(c[3]);
        *(ushort4*)((unsigned short*)cur_out + (size_t)n * 64 + q * 4) = o;
    } else {
        float4 o; o.x = c[0]; o.y = c[1]; o.z = c[2]; o.w = c[3];
        *(float4*)((float*)cur_out + (size_t)n * 64 + q * 4) = o;
    }
}

extern "C" void kernel_launch(void* const* d_in, const int* in_sizes, int n_in,
                              void* d_out, int out_size, void* d_ws, size_t ws_size,
                              hipStream_t stream) {
    (void)in_sizes; (void)n_in; (void)out_size; (void)ws_size;

    const void* x  = d_in[0];               // [N,64]
    const int*  ei = (const int*)d_in[1];   // [2,E]
    const void* ew = d_in[2];               // [E]
    // d_in[3] = edge_attr, unused
    const void* w0 = d_in[4];               // [64,64]
    const void* b0 = d_in[5];               // [64]
    const void* w1 = d_in[6];               // [2,64,64]

    // ws layout (~40.5 MB); all int4-stored arrays 16B-aligned
    int*   flags    = (int*)d_ws;                     // 64 ints
    float* deg      = (float*)d_ws + 64;              // NN f32
    int*   cnt      = (int*)(deg + NN);               // NN int
    float* dinv     = (float*)(cnt + NN);             // NN f32
    int*   ptr      = (int*)(dinv + NN);              // NN+4 int
    int*   cursor   = ptr + NN + 4;                   // NN int
    int*   blocksum = cursor + NN;                    // 128 int
    int*   blockoff = blocksum + 128;                 // 132 int
    int2*  edgedata = (int2*)(blockoff + 132);        // NE int2 (12.8 MB)
    unsigned short* h0b  = (unsigned short*)(edgedata + NE);   // NN*64 bf16
    unsigned short* curB = h0b + (size_t)NN * 64;              // NN*64 bf16

    k_probe<<<1, 256, 0, stream>>>((const unsigned short*)x, ei, flags);
    hipMemsetAsync(deg, 0, (size_t)2 * NN * sizeof(float), stream);  // deg + cnt
    k_deg<<<(NE + 255) / 256, 256, 0, stream>>>(ei, ew, deg, cnt, flags);
    k_dinv<<<(NN + 255) / 256, 256, 0, stream>>>(deg, dinv);
    k_scan1<<<SCAN_NB, 256, 0, stream>>>(cnt, blocksum);
    k_scan2<<<1, 128, 0, stream>>>(blocksum, blockoff);
    k_scan3<<<SCAN_NB, 256, 0, stream>>>(cnt, blockoff, ptr, cursor);
    k_fill<<<(NE + 255) / 256, 256, 0, stream>>>(ei, ew, dinv, cursor, edgedata, flags);
    k_h0<<<(NN + 63) / 64, 256, 0, stream>>>(x, w0, b0, h0b, d_out, flags);

    int grid = (NN + 15) / 16;
    // layer 0: read d_out, write curB; layer 1: read curB, write d_out
    k_conv<<<grid, 256, 0, stream>>>(ptr, edgedata, d_out, h0b, w1, curB, 0, flags);
    k_conv<<<grid, 256, 0, stream>>>(ptr, edgedata, curB, h0b, w1, d_out, 1, flags);
}

// Round 6
// 711.235 us; speedup vs baseline: 1.0089x; 1.0089x over previous
//
#include <hip/hip_runtime.h>

#define NN 100000
#define NE 1600000
#define SCAN_NB 98   // ceil(NN / 1024)

typedef __attribute__((ext_vector_type(8))) short bf16x8;
typedef __attribute__((ext_vector_type(4))) float floatx4;

static __device__ __forceinline__ float bitsf(unsigned u) {
    union { unsigned u; float f; } t; t.u = u; return t.f;
}
static __device__ __forceinline__ unsigned fbits(float f) {
    union { float f; unsigned u; } t; t.f = f; return t.u;
}

static __device__ __forceinline__ unsigned short f2bf(float f) {
    union { float f; unsigned u; } t; t.f = f;
    unsigned r = t.u + 0x7fffu + ((t.u >> 16) & 1u);  // RNE
    return (unsigned short)(r >> 16);
}

// load 4 consecutive bf16 (8B) and widen to f32
static __device__ __forceinline__ void ld_bf4(const unsigned short* p, float* f) {
    uint2 u = *reinterpret_cast<const uint2*>(p);
    f[0] = bitsf(u.x << 16);
    f[1] = bitsf(u.x & 0xffff0000u);
    f[2] = bitsf(u.y << 16);
    f[3] = bitsf(u.y & 0xffff0000u);
}

static __device__ __forceinline__ float ldf(const void* p, int i, int fb) {
    return fb ? bitsf(((unsigned)((const unsigned short*)p)[i]) << 16)
              : ((const float*)p)[i];
}

static __device__ __forceinline__ int ld_row(const int* ei, int e, int i64) {
    return i64 ? ei[2 * e] : ei[e];
}
static __device__ __forceinline__ int ld_col(const int* ei, int e, int i64) {
    return i64 ? ei[2 * NE + 2 * e] : ei[NE + e];
}

// ---- probe input dtypes (deterministic) -----------------------------------
__global__ void k_probe(const unsigned short* __restrict__ xs, const int* __restrict__ ei,
                        int* __restrict__ flags) {
    __shared__ int s_bad[256], s_odd[256];
    int t = threadIdx.x;
    int bad = 0;
    for (int i = 0; i < 16; i++) {
        unsigned short v = xs[t * 16 + i];
        if (((v >> 7) & 0xFF) >= 0xC0) bad++;
    }
    s_bad[t] = bad;
    s_odd[t] = (ei[2 * t + 1] != 0) ? 1 : 0;
    __syncthreads();
    if (t == 0) {
        int B = 0, O = 0;
        for (int i = 0; i < 256; i++) { B += s_bad[i]; O += s_odd[i]; }
        flags[0] = (B < 16) ? 1 : 0;  // 1 = floats stored as bf16
        flags[1] = (O == 0) ? 1 : 0;  // 1 = edge_index stored as int64
    }
}

// ---- deg[c] += ew[e]; cnt[c] += 1 -----------------------------------------
__global__ void k_deg(const int* __restrict__ ei, const void* __restrict__ ew,
                      float* __restrict__ deg, int* __restrict__ cnt,
                      const int* __restrict__ flags) {
    int e = blockIdx.x * 256 + threadIdx.x;
    if (e >= NE) return;
    int fb = flags[0], i64 = flags[1];
    int c = ld_col(ei, e, i64);
    atomicAdd(&deg[c], ldf(ew, e, fb));
    atomicAdd(&cnt[c], 1);
}

__global__ void k_dinv(const float* __restrict__ deg, float* __restrict__ dinv) {
    int n = blockIdx.x * 256 + threadIdx.x;
    if (n < NN) {
        float d = deg[n];
        dinv[n] = (d > 0.f) ? rsqrtf(d) : 0.f;
    }
}

// ---- hierarchical scan: cnt -> ptr (exclusive), cursor --------------------
__global__ void k_scan1(const int* __restrict__ cnt, int* __restrict__ blocksum) {
    __shared__ int s[256];
    int b = blockIdx.x, t = threadIdx.x;
    int base = b * 1024 + t * 4;
    int v = 0;
    if (base + 3 < NN) {
        int4 c = *(const int4*)(cnt + base);
        v = c.x + c.y + c.z + c.w;
    } else {
        for (int i = 0; i < 4; i++) if (base + i < NN) v += cnt[base + i];
    }
    s[t] = v;
    __syncthreads();
    for (int off = 128; off > 0; off >>= 1) {
        if (t < off) s[t] += s[t + off];
        __syncthreads();
    }
    if (t == 0) blocksum[b] = s[0];
}

__global__ void k_scan2(const int* __restrict__ blocksum, int* __restrict__ blockoff) {
    __shared__ int s[128];
    int t = threadIdx.x;
    int v = (t < SCAN_NB) ? blocksum[t] : 0;
    s[t] = v;
    __syncthreads();
    for (int off = 1; off < 128; off <<= 1) {
        int u = (t >= off) ? s[t - off] : 0;
        __syncthreads();
        s[t] += u;
        __syncthreads();
    }
    if (t < SCAN_NB) blockoff[t] = s[t] - v;   // exclusive
    if (t == SCAN_NB - 1) blockoff[SCAN_NB] = s[t];  // total
}

__global__ void k_scan3(const int* __restrict__ cnt, const int* __restrict__ blockoff,
                        int* __restrict__ ptr, int* __restrict__ cursor) {
    __shared__ int s[256];
    int b = blockIdx.x, t = threadIdx.x;
    int base = b * 1024 + t * 4;
    int c[4] = {0, 0, 0, 0};
    if (base + 3 < NN) {
        int4 cc = *(const int4*)(cnt + base);
        c[0] = cc.x; c[1] = cc.y; c[2] = cc.z; c[3] = cc.w;
    } else {
        for (int i = 0; i < 4; i++) if (base + i < NN) c[i] = cnt[base + i];
    }
    int tsum = c[0] + c[1] + c[2] + c[3];
    s[t] = tsum;
    __syncthreads();
    for (int off = 1; off < 256; off <<= 1) {
        int u = (t >= off) ? s[t - off] : 0;
        __syncthreads();
        s[t] += u;
        __syncthreads();
    }
    int run = blockoff[b] + s[t] - tsum;
    int p[4];
#pragma unroll
    for (int i = 0; i < 4; i++) { p[i] = run; run += c[i]; }
    if (base + 3 < NN) {
        int4 pv; pv.x = p[0]; pv.y = p[1]; pv.z = p[2]; pv.w = p[3];
        *(int4*)(ptr + base) = pv;
        *(int4*)(cursor + base) = pv;
    } else {
        for (int i = 0; i < 4; i++) if (base + i < NN) { ptr[base + i] = p[i]; cursor[base + i] = p[i]; }
    }
    if (b == 0 && t == 0) ptr[NN] = blockoff[SCAN_NB];
}

// ---- fill CSR: edgedata[pos] = (row, norm_bits) ----------------------------
__global__ void k_fill(const int* __restrict__ ei, const void* __restrict__ ew,
                       const float* __restrict__ dinv, int* __restrict__ cursor,
                       int2* __restrict__ edgedata, const int* __restrict__ flags) {
    int e = blockIdx.x * 256 + threadIdx.x;
    if (e >= NE) return;
    int fb = flags[0], i64 = flags[1];
    int r = ld_row(ei, e, i64), c = ld_col(ei, e, i64);
    float nw = dinv[r] * ldf(ew, e, fb) * dinv[c];
    int pos = atomicAdd(&cursor[c], 1);
    int2 ed; ed.x = r; ed.y = (int)fbits(nw);
    edgedata[pos] = ed;
}

// ---- h0 = relu(x @ W0^T + b) -> h0b only (NO d_out write) ------------------
// MFMA path: block = 4 waves; wave = 16 nodes x 64 feats.
__global__ void k_h0(const void* __restrict__ x, const void* __restrict__ w0,
                     const void* __restrict__ b0, unsigned short* __restrict__ h0b,
                     const int* __restrict__ flags) {
    int fb = flags[0];
    if (fb) {
        __shared__ float s_o[4][16][68];   // [wave][node][feat], +4 pad
        int tid = threadIdx.x;
        int w = tid >> 6, l = tid & 63;
        int quad = l >> 4, m = l & 15;
        int nodebase = blockIdx.x * 64 + w * 16;

        int arow = nodebase + m;
        if (arow > NN - 1) arow = NN - 1;
        const unsigned short* xp = (const unsigned short*)x + (size_t)arow * 64 + quad * 8;
        bf16x8 a_lo = *(const bf16x8*)xp;
        bf16x8 a_hi = *(const bf16x8*)(xp + 32);

        floatx4 acc[4];
#pragma unroll
        for (int t = 0; t < 4; t++) acc[t] = (floatx4){0.f, 0.f, 0.f, 0.f};

        const unsigned short* wp = (const unsigned short*)w0;
#pragma unroll
        for (int t = 0; t < 4; t++) {
            const unsigned short* wrow = wp + (size_t)(t * 16 + m) * 64 + quad * 8;
            bf16x8 b_lo = *(const bf16x8*)wrow;
            bf16x8 b_hi = *(const bf16x8*)(wrow + 32);
            acc[t] = __builtin_amdgcn_mfma_f32_16x16x32_bf16(a_lo, b_lo, acc[t], 0, 0, 0);
            acc[t] = __builtin_amdgcn_mfma_f32_16x16x32_bf16(a_hi, b_hi, acc[t], 0, 0, 0);
        }

        const unsigned short* bp = (const unsigned short*)b0;
#pragma unroll
        for (int t = 0; t < 4; t++) {
            float bias = bitsf(((unsigned)bp[t * 16 + m]) << 16);
#pragma unroll
            for (int r = 0; r < 4; r++) {
                float v = acc[t][r] + bias;
                s_o[w][quad * 4 + r][t * 16 + m] = (v > 0.f) ? v : 0.f;
            }
        }
        __syncthreads();

        int node = l >> 2, chunk = l & 3;   // 16 nodes x 4 chunks of 16 feats
        int gnode = nodebase + node;
        if (gnode < NN) {
            union { unsigned short us[16]; uint4 u4[2]; } ob;
#pragma unroll
            for (int i = 0; i < 16; i += 4) {
                float4 v = *(const float4*)&s_o[w][node][chunk * 16 + i];
                ob.us[i + 0] = f2bf(v.x);
                ob.us[i + 1] = f2bf(v.y);
                ob.us[i + 2] = f2bf(v.z);
                ob.us[i + 3] = f2bf(v.w);
            }
            uint4* hp = (uint4*)(h0b + (size_t)gnode * 64 + chunk * 16);
            hp[0] = ob.u4[0]; hp[1] = ob.u4[1];
        }
    } else {
        // f32-input fallback (never taken for this dataset; correctness insurance)
        for (int s = 0; s < 4; s++) {
            int t = blockIdx.x * 1024 + s * 256 + threadIdx.x;
            int n = t >> 4, q = t & 15;
            if (n >= NN) continue;
            float acc[4] = {0.f, 0.f, 0.f, 0.f};
            const float* xp = (const float*)x + (size_t)n * 64;
            const float* wp = (const float*)w0;
            for (int kk = 0; kk < 64; kk += 4) {
                float4 xv = *(const float4*)(xp + kk);
                for (int j = 0; j < 4; j++) {
                    float4 wv = *(const float4*)(wp + (size_t)(q * 4 + j) * 64 + kk);
                    acc[j] += xv.x * wv.x + xv.y * wv.y + xv.z * wv.z + xv.w * wv.w;
                }
            }
            float r[4];
            for (int j = 0; j < 4; j++) {
                float v = acc[j] + ((const float*)b0)[q * 4 + j];
                r[j] = (v > 0.f) ? v : 0.f;
            }
            ushort4 hb;
            hb.x = f2bf(r[0]); hb.y = f2bf(r[1]); hb.z = f2bf(r[2]); hb.w = f2bf(r[3]);
            *(ushort4*)(h0b + (size_t)n * 64 + q * 4) = hb;
        }
    }
}

// ---- fused conv: gather + (0.1*agg+0.9*h0)@W1 relu + residual --------------
// cur_in is ALWAYS a bf16 ws buffer (h0b for layer 0, curB for layer 1).
__global__ void k_conv(const int* __restrict__ ptr, const int2* __restrict__ edgedata,
                       const unsigned short* __restrict__ cur_in,
                       const unsigned short* __restrict__ h0b,
                       const void* __restrict__ w1, void* __restrict__ cur_out,
                       int layer, const int* __restrict__ flags) {
    __shared__ float s_w[64 * 64];       // 16 KB, W1 as f32
    __shared__ float s_t[16 * 68];       // padded stride 68
    int fb = flags[0];
    int out_bf = fb ? 1 : (layer == 0);

    int tid = threadIdx.x;
    if (fb) {
        const unsigned short* wp = (const unsigned short*)w1 + layer * 4096;
        for (int i = 0; i < 16; i += 4) {
            int idx = tid * 16 + i;
            float wv[4]; ld_bf4(wp + idx, wv);
            s_w[idx] = wv[0]; s_w[idx + 1] = wv[1]; s_w[idx + 2] = wv[2]; s_w[idx + 3] = wv[3];
        }
    } else {
        const float* wp = (const float*)w1 + layer * 4096;
        for (int i = 0; i < 16; i += 4) {
            int idx = tid * 16 + i;
            float4 wv = *(const float4*)(wp + idx);
            s_w[idx] = wv.x; s_w[idx + 1] = wv.y; s_w[idx + 2] = wv.z; s_w[idx + 3] = wv.w;
        }
    }

    int g = tid >> 4, q = tid & 15;
    int n = blockIdx.x * 16 + g;
    float acc[4] = {0.f, 0.f, 0.f, 0.f};
    if (n < NN) {
        int jb = ptr[n], je = ptr[n + 1];
        for (int j = jb; j < je; j++) {
            int2 ed = edgedata[j];
            float w = bitsf((unsigned)ed.y);
            float v[4];
            ld_bf4(cur_in + (size_t)ed.x * 64 + q * 4, v);
            acc[0] += v[0] * w; acc[1] += v[1] * w;
            acc[2] += v[2] * w; acc[3] += v[3] * w;
        }
        float hv[4]; ld_bf4(h0b + (size_t)n * 64 + q * 4, hv);
#pragma unroll
        for (int j = 0; j < 4; j++)
            s_t[g * 68 + q * 4 + j] = 0.1f * acc[j] + 0.9f * hv[j];
    }
    __syncthreads();
    if (n >= NN) return;

    float acc2[4] = {0.f, 0.f, 0.f, 0.f};
#pragma unroll 8
    for (int k = 0; k < 64; k++) {
        float tv = s_t[g * 68 + k];
        float4 wv = *(const float4*)(&s_w[k * 64 + q * 4]);
        acc2[0] += tv * wv.x; acc2[1] += tv * wv.y;
        acc2[2] += tv * wv.z; acc2[3] += tv * wv.w;
    }
    float c[4];
    ld_bf4(cur_in + (size_t)n * 64 + q * 4, c);
#pragma unroll
    for (int j = 0; j < 4; j++) c[j] += (acc2[j] > 0.f) ? acc2[j] : 0.f;
    if (out_bf) {
        ushort4 o;
        o.x = f2bf(c[0]); o.y = f2bf(c[1]); o.z = f2bf(c[2]); o.w = f2bf(c[3]);
        *(ushort4*)((unsigned short*)cur_out + (size_t)n * 64 + q * 4) = o;
    } else {
        float4 o; o.x = c[0]; o.y = c[1]; o.z = c[2]; o.w = c[3];
        *(float4*)((float*)cur_out + (size_t)n * 64 + q * 4) = o;
    }
}

extern "C" void kernel_launch(void* const* d_in, const int* in_sizes, int n_in,
                              void* d_out, int out_size, void* d_ws, size_t ws_size,
                              hipStream_t stream) {
    (void)in_sizes; (void)n_in; (void)out_size; (void)ws_size;

    const void* x  = d_in[0];               // [N,64]
    const int*  ei = (const int*)d_in[1];   // [2,E]
    const void* ew = d_in[2];               // [E]
    // d_in[3] = edge_attr, unused
    const void* w0 = d_in[4];               // [64,64]
    const void* b0 = d_in[5];               // [64]
    const void* w1 = d_in[6];               // [2,64,64]

    // ws layout (~40.5 MB); all int4-stored arrays 16B-aligned
    int*   flags    = (int*)d_ws;                     // 64 ints
    float* deg      = (float*)d_ws + 64;              // NN f32
    int*   cnt      = (int*)(deg + NN);               // NN int
    float* dinv     = (float*)(cnt + NN);             // NN f32
    int*   ptr      = (int*)(dinv + NN);              // NN+4 int
    int*   cursor   = ptr + NN + 4;                   // NN int
    int*   blocksum = cursor + NN;                    // 128 int
    int*   blockoff = blocksum + 128;                 // 132 int
    int2*  edgedata = (int2*)(blockoff + 132);        // NE int2 (12.8 MB)
    unsigned short* h0b  = (unsigned short*)(edgedata + NE);   // NN*64 bf16
    unsigned short* curB = h0b + (size_t)NN * 64;              // NN*64 bf16

    k_probe<<<1, 256, 0, stream>>>((const unsigned short*)x, ei, flags);
    hipMemsetAsync(deg, 0, (size_t)2 * NN * sizeof(float), stream);  // deg + cnt
    k_deg<<<(NE + 255) / 256, 256, 0, stream>>>(ei, ew, deg, cnt, flags);
    k_dinv<<<(NN + 255) / 256, 256, 0, stream>>>(deg, dinv);
    k_scan1<<<SCAN_NB, 256, 0, stream>>>(cnt, blocksum);
    k_scan2<<<1, 128, 0, stream>>>(blocksum, blockoff);
    k_scan3<<<SCAN_NB, 256, 0, stream>>>(cnt, blockoff, ptr, cursor);
    k_fill<<<(NE + 255) / 256, 256, 0, stream>>>(ei, ew, dinv, cursor, edgedata, flags);
    k_h0<<<(NN + 63) / 64, 256, 0, stream>>>(x, w0, b0, h0b, flags);

    int grid = (NN + 15) / 16;
    // layer 0: cur_in = h0b (cur == h0), write curB; layer 1: read curB, write d_out
    k_conv<<<grid, 256, 0, stream>>>(ptr, edgedata, h0b, h0b, w1, curB, 0, flags);
    k_conv<<<grid, 256, 0, stream>>>(ptr, edgedata, curB, h0b, w1, d_out, 1, flags);
}

// Round 7
// 687.586 us; speedup vs baseline: 1.0436x; 1.0344x over previous
//
#include <hip/hip_runtime.h>

#define NN 100000
#define NE 1600000
#define SCAN_NB 98   // ceil(NN / 1024)

typedef __attribute__((ext_vector_type(8))) short bf16x8;
typedef __attribute__((ext_vector_type(4))) float floatx4;

static __device__ __forceinline__ float bitsf(unsigned u) {
    union { unsigned u; float f; } t; t.u = u; return t.f;
}
static __device__ __forceinline__ unsigned fbits(float f) {
    union { float f; unsigned u; } t; t.f = f; return t.u;
}

static __device__ __forceinline__ unsigned short f2bf(float f) {
    union { float f; unsigned u; } t; t.f = f;
    unsigned r = t.u + 0x7fffu + ((t.u >> 16) & 1u);  // RNE
    return (unsigned short)(r >> 16);
}

// load 4 consecutive bf16 (8B) and widen to f32
static __device__ __forceinline__ void ld_bf4(const unsigned short* p, float* f) {
    uint2 u = *reinterpret_cast<const uint2*>(p);
    f[0] = bitsf(u.x << 16);
    f[1] = bitsf(u.x & 0xffff0000u);
    f[2] = bitsf(u.y << 16);
    f[3] = bitsf(u.y & 0xffff0000u);
}

static __device__ __forceinline__ float ldf(const void* p, int i, int fb) {
    return fb ? bitsf(((unsigned)((const unsigned short*)p)[i]) << 16)
              : ((const float*)p)[i];
}

static __device__ __forceinline__ int ld_row(const int* ei, int e, int i64) {
    return i64 ? ei[2 * e] : ei[e];
}
static __device__ __forceinline__ int ld_col(const int* ei, int e, int i64) {
    return i64 ? ei[2 * NE + 2 * e] : ei[NE + e];
}

// ---- probe input dtypes (deterministic) -----------------------------------
__global__ void k_probe(const unsigned short* __restrict__ xs, const int* __restrict__ ei,
                        int* __restrict__ flags) {
    __shared__ int s_bad[256], s_odd[256];
    int t = threadIdx.x;
    int bad = 0;
    for (int i = 0; i < 16; i++) {
        unsigned short v = xs[t * 16 + i];
        if (((v >> 7) & 0xFF) >= 0xC0) bad++;
    }
    s_bad[t] = bad;
    s_odd[t] = (ei[2 * t + 1] != 0) ? 1 : 0;
    __syncthreads();
    if (t == 0) {
        int B = 0, O = 0;
        for (int i = 0; i < 256; i++) { B += s_bad[i]; O += s_odd[i]; }
        flags[0] = (B < 16) ? 1 : 0;  // 1 = floats stored as bf16
        flags[1] = (O == 0) ? 1 : 0;  // 1 = edge_index stored as int64
    }
}

// ---- deg[c] += ew[e]; cnt[c] += 1 -----------------------------------------
__global__ void k_deg(const int* __restrict__ ei, const void* __restrict__ ew,
                      float* __restrict__ deg, int* __restrict__ cnt,
                      const int* __restrict__ flags) {
    int e = blockIdx.x * 256 + threadIdx.x;
    if (e >= NE) return;
    int fb = flags[0], i64 = flags[1];
    int c = ld_col(ei, e, i64);
    atomicAdd(&deg[c], ldf(ew, e, fb));
    atomicAdd(&cnt[c], 1);
}

__global__ void k_dinv(const float* __restrict__ deg, float* __restrict__ dinv) {
    int n = blockIdx.x * 256 + threadIdx.x;
    if (n < NN) {
        float d = deg[n];
        dinv[n] = (d > 0.f) ? rsqrtf(d) : 0.f;
    }
}

// ---- hierarchical scan: cnt -> ptr (exclusive), cursor --------------------
__global__ void k_scan1(const int* __restrict__ cnt, int* __restrict__ blocksum) {
    __shared__ int s[256];
    int b = blockIdx.x, t = threadIdx.x;
    int base = b * 1024 + t * 4;
    int v = 0;
    if (base + 3 < NN) {
        int4 c = *(const int4*)(cnt + base);
        v = c.x + c.y + c.z + c.w;
    } else {
        for (int i = 0; i < 4; i++) if (base + i < NN) v += cnt[base + i];
    }
    s[t] = v;
    __syncthreads();
    for (int off = 128; off > 0; off >>= 1) {
        if (t < off) s[t] += s[t + off];
        __syncthreads();
    }
    if (t == 0) blocksum[b] = s[0];
}

__global__ void k_scan2(const int* __restrict__ blocksum, int* __restrict__ blockoff) {
    __shared__ int s[128];
    int t = threadIdx.x;
    int v = (t < SCAN_NB) ? blocksum[t] : 0;
    s[t] = v;
    __syncthreads();
    for (int off = 1; off < 128; off <<= 1) {
        int u = (t >= off) ? s[t - off] : 0;
        __syncthreads();
        s[t] += u;
        __syncthreads();
    }
    if (t < SCAN_NB) blockoff[t] = s[t] - v;   // exclusive
    if (t == SCAN_NB - 1) blockoff[SCAN_NB] = s[t];  // total
}

__global__ void k_scan3(const int* __restrict__ cnt, const int* __restrict__ blockoff,
                        int* __restrict__ ptr, int* __restrict__ cursor) {
    __shared__ int s[256];
    int b = blockIdx.x, t = threadIdx.x;
    int base = b * 1024 + t * 4;
    int c[4] = {0, 0, 0, 0};
    if (base + 3 < NN) {
        int4 cc = *(const int4*)(cnt + base);
        c[0] = cc.x; c[1] = cc.y; c[2] = cc.z; c[3] = cc.w;
    } else {
        for (int i = 0; i < 4; i++) if (base + i < NN) c[i] = cnt[base + i];
    }
    int tsum = c[0] + c[1] + c[2] + c[3];
    s[t] = tsum;
    __syncthreads();
    for (int off = 1; off < 256; off <<= 1) {
        int u = (t >= off) ? s[t - off] : 0;
        __syncthreads();
        s[t] += u;
        __syncthreads();
    }
    int run = blockoff[b] + s[t] - tsum;
    int p[4];
#pragma unroll
    for (int i = 0; i < 4; i++) { p[i] = run; run += c[i]; }
    if (base + 3 < NN) {
        int4 pv; pv.x = p[0]; pv.y = p[1]; pv.z = p[2]; pv.w = p[3];
        *(int4*)(ptr + base) = pv;
        *(int4*)(cursor + base) = pv;
    } else {
        for (int i = 0; i < 4; i++) if (base + i < NN) { ptr[base + i] = p[i]; cursor[base + i] = p[i]; }
    }
    if (b == 0 && t == 0) ptr[NN] = blockoff[SCAN_NB];
}

// ---- fill CSR: edgedata[pos] = (row, norm_bits) ----------------------------
__global__ void k_fill(const int* __restrict__ ei, const void* __restrict__ ew,
                       const float* __restrict__ dinv, int* __restrict__ cursor,
                       int2* __restrict__ edgedata, const int* __restrict__ flags) {
    int e = blockIdx.x * 256 + threadIdx.x;
    if (e >= NE) return;
    int fb = flags[0], i64 = flags[1];
    int r = ld_row(ei, e, i64), c = ld_col(ei, e, i64);
    float nw = dinv[r] * ldf(ew, e, fb) * dinv[c];
    int pos = atomicAdd(&cursor[c], 1);
    int2 ed; ed.x = r; ed.y = (int)fbits(nw);
    edgedata[pos] = ed;
}

// ---- h0 = relu(x @ W0^T + b) -> h0b only -----------------------------------
// MFMA path: block = 4 waves; wave = 16 nodes x 64 feats.
__global__ void k_h0(const void* __restrict__ x, const void* __restrict__ w0,
                     const void* __restrict__ b0, unsigned short* __restrict__ h0b,
                     const int* __restrict__ flags) {
    int fb = flags[0];
    if (fb) {
        __shared__ float s_o[4][16][68];   // [wave][node][feat], +4 pad
        int tid = threadIdx.x;
        int w = tid >> 6, l = tid & 63;
        int quad = l >> 4, m = l & 15;
        int nodebase = blockIdx.x * 64 + w * 16;

        int arow = nodebase + m;
        if (arow > NN - 1) arow = NN - 1;
        const unsigned short* xp = (const unsigned short*)x + (size_t)arow * 64 + quad * 8;
        bf16x8 a_lo = *(const bf16x8*)xp;
        bf16x8 a_hi = *(const bf16x8*)(xp + 32);

        floatx4 acc[4];
#pragma unroll
        for (int t = 0; t < 4; t++) acc[t] = (floatx4){0.f, 0.f, 0.f, 0.f};

        const unsigned short* wp = (const unsigned short*)w0;
#pragma unroll
        for (int t = 0; t < 4; t++) {
            const unsigned short* wrow = wp + (size_t)(t * 16 + m) * 64 + quad * 8;
            bf16x8 b_lo = *(const bf16x8*)wrow;
            bf16x8 b_hi = *(const bf16x8*)(wrow + 32);
            acc[t] = __builtin_amdgcn_mfma_f32_16x16x32_bf16(a_lo, b_lo, acc[t], 0, 0, 0);
            acc[t] = __builtin_amdgcn_mfma_f32_16x16x32_bf16(a_hi, b_hi, acc[t], 0, 0, 0);
        }

        const unsigned short* bp = (const unsigned short*)b0;
#pragma unroll
        for (int t = 0; t < 4; t++) {
            float bias = bitsf(((unsigned)bp[t * 16 + m]) << 16);
#pragma unroll
            for (int r = 0; r < 4; r++) {
                float v = acc[t][r] + bias;
                s_o[w][quad * 4 + r][t * 16 + m] = (v > 0.f) ? v : 0.f;
            }
        }
        __syncthreads();

        int node = l >> 2, chunk = l & 3;   // 16 nodes x 4 chunks of 16 feats
        int gnode = nodebase + node;
        if (gnode < NN) {
            union { unsigned short us[16]; uint4 u4[2]; } ob;
#pragma unroll
            for (int i = 0; i < 16; i += 4) {
                float4 v = *(const float4*)&s_o[w][node][chunk * 16 + i];
                ob.us[i + 0] = f2bf(v.x);
                ob.us[i + 1] = f2bf(v.y);
                ob.us[i + 2] = f2bf(v.z);
                ob.us[i + 3] = f2bf(v.w);
            }
            uint4* hp = (uint4*)(h0b + (size_t)gnode * 64 + chunk * 16);
            hp[0] = ob.u4[0]; hp[1] = ob.u4[1];
        }
    } else {
        // f32-input fallback (never taken for this dataset; correctness insurance)
        for (int s = 0; s < 4; s++) {
            int t = blockIdx.x * 1024 + s * 256 + threadIdx.x;
            int n = t >> 4, q = t & 15;
            if (n >= NN) continue;
            float acc[4] = {0.f, 0.f, 0.f, 0.f};
            const float* xp = (const float*)x + (size_t)n * 64;
            const float* wp = (const float*)w0;
            for (int kk = 0; kk < 64; kk += 4) {
                float4 xv = *(const float4*)(xp + kk);
                for (int j = 0; j < 4; j++) {
                    float4 wv = *(const float4*)(wp + (size_t)(q * 4 + j) * 64 + kk);
                    acc[j] += xv.x * wv.x + xv.y * wv.y + xv.z * wv.z + xv.w * wv.w;
                }
            }
            float r[4];
            for (int j = 0; j < 4; j++) {
                float v = acc[j] + ((const float*)b0)[q * 4 + j];
                r[j] = (v > 0.f) ? v : 0.f;
            }
            ushort4 hb;
            hb.x = f2bf(r[0]); hb.y = f2bf(r[1]); hb.z = f2bf(r[2]); hb.w = f2bf(r[3]);
            *(ushort4*)(h0b + (size_t)n * 64 + q * 4) = hb;
        }
    }
}

// ---- fused conv: gather + (0.1*agg+0.9*h0)@W1 relu + residual --------------
// 16 lanes per node (within one wave). Edge metadata: coalesced chunk load +
// __shfl broadcast (kills the 16x-redundant edgedata loads); full chunks of 16
// unrolled for 16 gathers in flight per lane.
__global__ void k_conv(const int* __restrict__ ptr, const int2* __restrict__ edgedata,
                       const unsigned short* __restrict__ cur_in,
                       const unsigned short* __restrict__ h0b,
                       const void* __restrict__ w1, void* __restrict__ cur_out,
                       int layer, const int* __restrict__ flags) {
    __shared__ float s_w[64 * 64];       // 16 KB, W1 as f32
    __shared__ float s_t[16 * 68];       // padded stride 68
    int fb = flags[0];
    int out_bf = fb ? 1 : (layer == 0);

    int tid = threadIdx.x;
    if (fb) {
        const unsigned short* wp = (const unsigned short*)w1 + layer * 4096;
        for (int i = 0; i < 16; i += 4) {
            int idx = tid * 16 + i;
            float wv[4]; ld_bf4(wp + idx, wv);
            s_w[idx] = wv[0]; s_w[idx + 1] = wv[1]; s_w[idx + 2] = wv[2]; s_w[idx + 3] = wv[3];
        }
    } else {
        const float* wp = (const float*)w1 + layer * 4096;
        for (int i = 0; i < 16; i += 4) {
            int idx = tid * 16 + i;
            float4 wv = *(const float4*)(wp + idx);
            s_w[idx] = wv.x; s_w[idx + 1] = wv.y; s_w[idx + 2] = wv.z; s_w[idx + 3] = wv.w;
        }
    }

    int g = tid >> 4, q = tid & 15;
    int lane = tid & 63;
    int gbase = lane & 48;               // first lane of this node-group within the wave
    int n = blockIdx.x * 16 + g;
    float acc[4] = {0.f, 0.f, 0.f, 0.f};
    if (n < NN) {
        int jb = ptr[n], je = ptr[n + 1];
        int deg = je - jb;
        int nfull = deg & ~15;
        // full chunks of 16: coalesced edge-meta load, shfl broadcast, unrolled
        for (int j0 = jb; j0 < jb + nfull; j0 += 16) {
            int2 ed = edgedata[j0 + q];
#pragma unroll
            for (int i = 0; i < 16; i++) {
                int r = __shfl(ed.x, gbase + i, 64);
                float w = bitsf((unsigned)__shfl(ed.y, gbase + i, 64));
                float v[4];
                ld_bf4(cur_in + (size_t)r * 64 + q * 4, v);
                acc[0] += v[0] * w; acc[1] += v[1] * w;
                acc[2] += v[2] * w; acc[3] += v[3] * w;
            }
        }
        // tail
        int rem = deg - nfull;
        if (rem > 0) {
            int2 ed;
            if (q < rem) ed = edgedata[jb + nfull + q];
            else { ed.x = 0; ed.y = 0; }
            for (int i = 0; i < rem; i++) {
                int r = __shfl(ed.x, gbase + i, 64);
                float w = bitsf((unsigned)__shfl(ed.y, gbase + i, 64));
                float v[4];
                ld_bf4(cur_in + (size_t)r * 64 + q * 4, v);
                acc[0] += v[0] * w; acc[1] += v[1] * w;
                acc[2] += v[2] * w; acc[3] += v[3] * w;
            }
        }
        float hv[4]; ld_bf4(h0b + (size_t)n * 64 + q * 4, hv);
#pragma unroll
        for (int j = 0; j < 4; j++)
            s_t[g * 68 + q * 4 + j] = 0.1f * acc[j] + 0.9f * hv[j];
    }
    __syncthreads();
    if (n >= NN) return;

    float acc2[4] = {0.f, 0.f, 0.f, 0.f};
#pragma unroll 8
    for (int k = 0; k < 64; k++) {
        float tv = s_t[g * 68 + k];
        float4 wv = *(const float4*)(&s_w[k * 64 + q * 4]);
        acc2[0] += tv * wv.x; acc2[1] += tv * wv.y;
        acc2[2] += tv * wv.z; acc2[3] += tv * wv.w;
    }
    float c[4];
    ld_bf4(cur_in + (size_t)n * 64 + q * 4, c);
#pragma unroll
    for (int j = 0; j < 4; j++) c[j] += (acc2[j] > 0.f) ? acc2[j] : 0.f;
    if (out_bf) {
        ushort4 o;
        o.x = f2bf(c[0]); o.y = f2bf(c[1]); o.z = f2bf(c[2]); o.w = f2bf(c[3]);
        *(ushort4*)((unsigned short*)cur_out + (size_t)n * 64 + q * 4) = o;
    } else {
        float4 o; o.x = c[0]; o.y = c[1]; o.z = c[2]; o.w = c[3];
        *(float4*)((float*)cur_out + (size_t)n * 64 + q * 4) = o;
    }
}

extern "C" void kernel_launch(void* const* d_in, const int* in_sizes, int n_in,
                              void* d_out, int out_size, void* d_ws, size_t ws_size,
                              hipStream_t stream) {
    (void)in_sizes; (void)n_in; (void)out_size; (void)ws_size;

    const void* x  = d_in[0];               // [N,64]
    const int*  ei = (const int*)d_in[1];   // [2,E]
    const void* ew = d_in[2];               // [E]
    // d_in[3] = edge_attr, unused
    const void* w0 = d_in[4];               // [64,64]
    const void* b0 = d_in[5];               // [64]
    const void* w1 = d_in[6];               // [2,64,64]

    // ws layout (~40.5 MB); all int4-stored arrays 16B-aligned
    int*   flags    = (int*)d_ws;                     // 64 ints
    float* deg      = (float*)d_ws + 64;              // NN f32
    int*   cnt      = (int*)(deg + NN);               // NN int
    float* dinv     = (float*)(cnt + NN);             // NN f32
    int*   ptr      = (int*)(dinv + NN);              // NN+4 int
    int*   cursor   = ptr + NN + 4;                   // NN int
    int*   blocksum = cursor + NN;                    // 128 int
    int*   blockoff = blocksum + 128;                 // 132 int
    int2*  edgedata = (int2*)(blockoff + 132);        // NE int2 (12.8 MB)
    unsigned short* h0b  = (unsigned short*)(edgedata + NE);   // NN*64 bf16
    unsigned short* curB = h0b + (size_t)NN * 64;              // NN*64 bf16

    k_probe<<<1, 256, 0, stream>>>((const unsigned short*)x, ei, flags);
    // REORDERED: k_h0 runs早 (depends only on probe) — diagnostic for the
    // post-atomic-kernel stall: if the ~200us k_h0 anomaly was inherited from
    // k_fill's position, it collapses here and moves onto conv0.
    k_h0<<<(NN + 63) / 64, 256, 0, stream>>>(x, w0, b0, h0b, flags);
    hipMemsetAsync(deg, 0, (size_t)2 * NN * sizeof(float), stream);  // deg + cnt
    k_deg<<<(NE + 255) / 256, 256, 0, stream>>>(ei, ew, deg, cnt, flags);
    k_dinv<<<(NN + 255) / 256, 256, 0, stream>>>(deg, dinv);
    k_scan1<<<SCAN_NB, 256, 0, stream>>>(cnt, blocksum);
    k_scan2<<<1, 128, 0, stream>>>(blocksum, blockoff);
    k_scan3<<<SCAN_NB, 256, 0, stream>>>(cnt, blockoff, ptr, cursor);
    k_fill<<<(NE + 255) / 256, 256, 0, stream>>>(ei, ew, dinv, cursor, edgedata, flags);

    int grid = (NN + 15) / 16;
    // layer 0: cur_in = h0b (cur == h0), write curB; layer 1: read curB, write d_out
    k_conv<<<grid, 256, 0, stream>>>(ptr, edgedata, h0b, h0b, w1, curB, 0, flags);
    k_conv<<<grid, 256, 0, stream>>>(ptr, edgedata, curB, h0b, w1, d_out, 1, flags);
}